// Round 1
// baseline (831.597 us; speedup 1.0000x reference)
//
#include <hip/hip_runtime.h>
#include <cstdint>

typedef unsigned short u16;
typedef __bf16 bf16x8 __attribute__((ext_vector_type(8)));
typedef float f32x4 __attribute__((ext_vector_type(4)));

__device__ __forceinline__ u16 f2bf(float f) {
  union { float f; uint32_t u; } x; x.f = f;
  uint32_t r = x.u + 0x7FFFu + ((x.u >> 16) & 1u);
  return (u16)(r >> 16);
}
__device__ __forceinline__ bf16x8 ld8s(const u16* p) {
  return *reinterpret_cast<const bf16x8*>(p);
}
__device__ __forceinline__ float geluf(float x) {
  return 0.5f * x * (1.f + erff(x * 0.70710678118654752f));
}

// ---------- transpose + f32->bf16 convert: out[orow][k] = in[k][n] ----------
// mode 0: orow = row_off + n.  mode 1 (GEGLU interleave, N=8192):
//   n < 4096  (a col):    orow = (n/16)*32 + n%16
//   n >= 4096 (gate col): orow = ((n-4096)/16)*32 + 16 + (n-4096)%16
__global__ void tcvt_kernel(const float* __restrict__ in, u16* __restrict__ out,
                            int K, int N, int mode, int row_off, int ldo) {
  __shared__ float tile[32][33];
  int n = blockIdx.x * 32 + threadIdx.x;
  int kbase = blockIdx.y * 32;
#pragma unroll
  for (int r = 0; r < 4; ++r) {
    int k = kbase + threadIdx.y + r * 8;
    tile[threadIdx.y + r * 8][threadIdx.x] = in[(size_t)k * N + n];
  }
  __syncthreads();
#pragma unroll
  for (int r = 0; r < 4; ++r) {
    int nl = threadIdx.y + r * 8;
    int ng = blockIdx.x * 32 + nl;
    int orow;
    if (mode == 0) {
      orow = row_off + ng;
    } else {
      if (ng < 4096) orow = ((ng >> 4) << 5) + (ng & 15);
      else { int t2 = ng - 4096; orow = ((t2 >> 4) << 5) + 16 + (t2 & 15); }
    }
    int k = kbase + threadIdx.x;
    out[(size_t)orow * ldo + k] = f2bf(tile[threadIdx.x][nl]);
  }
}

// ---------- GEGLU bias remap: b1p[n'] = ff_b1[src_col(n')] ----------
__global__ void b1remap_kernel(const float* __restrict__ b1, float* __restrict__ b1p) {
  int i = blockIdx.x * 256 + threadIdx.x;  // 8192 total
  int g = i >> 5, s = i & 31;
  int c = (s < 16) ? (g * 16 + s) : (4096 + g * 16 + (s - 16));
  b1p[i] = b1[c];
}

// ---------- elementwise f32 -> bf16 ----------
__global__ void cvt_kernel(const float* __restrict__ in, u16* __restrict__ out, int n) {
  int i = blockIdx.x * 256 + threadIdx.x;
  if (i < n) out[i] = f2bf(in[i]);
}

// ---------- hint + sinusoidal PE -> bf16 ----------
__global__ void peadd_kernel(const float* __restrict__ hint, u16* __restrict__ out) {
  int row = blockIdx.x;            // b*250 + t
  int t = row % 250;
  int tid = threadIdx.x;           // 256 threads, 4 elems each
  int d0 = tid * 4;
  int i0 = d0 >> 1;                // pair index
  float den0 = powf(10000.f, (float)i0 / 512.f);
  float den1 = powf(10000.f, (float)(i0 + 1) / 512.f);
  float a0 = (float)t / den0, a1 = (float)t / den1;
  const float* hp = hint + (size_t)row * 1024 + d0;
  u16* op = out + (size_t)row * 1024 + d0;
  op[0] = f2bf(hp[0] + sinf(a0));
  op[1] = f2bf(hp[1] + cosf(a0));
  op[2] = f2bf(hp[2] + sinf(a1));
  op[3] = f2bf(hp[3] + cosf(a1));
}

// ---------- LayerNorm: f32 [rows][1024] -> bf16 ----------
__global__ __launch_bounds__(256) void ln_kernel(const float* __restrict__ x,
                                                 const float* __restrict__ g,
                                                 const float* __restrict__ b,
                                                 u16* __restrict__ out) {
  int row = blockIdx.x;
  int tid = threadIdx.x;
  int l = tid & 63, w = tid >> 6;
  const float4 v = reinterpret_cast<const float4*>(x + (size_t)row * 1024)[tid];
  float s = v.x + v.y + v.z + v.w;
#pragma unroll
  for (int d = 1; d < 64; d <<= 1) s += __shfl_xor(s, d, 64);
  __shared__ float red[8];
  if (l == 0) red[w] = s;
  __syncthreads();
  float mean = (red[0] + red[1] + red[2] + red[3]) * (1.f / 1024.f);
  float dx = v.x - mean, dy = v.y - mean, dz = v.z - mean, dw = v.w - mean;
  float vs = dx * dx + dy * dy + dz * dz + dw * dw;
#pragma unroll
  for (int d = 1; d < 64; d <<= 1) vs += __shfl_xor(vs, d, 64);
  if (l == 0) red[4 + w] = vs;
  __syncthreads();
  float var = (red[4] + red[5] + red[6] + red[7]) * (1.f / 1024.f);
  float rstd = rsqrtf(var + 1e-5f);
  const float4 g4 = reinterpret_cast<const float4*>(g)[tid];
  const float4 b4 = reinterpret_cast<const float4*>(b)[tid];
  ushort4 o;
  o.x = f2bf(dx * rstd * g4.x + b4.x);
  o.y = f2bf(dy * rstd * g4.y + b4.y);
  o.z = f2bf(dz * rstd * g4.z + b4.z);
  o.w = f2bf(dw * rstd * g4.w + b4.w);
  reinterpret_cast<ushort4*>(out + (size_t)row * 1024)[tid] = o;
}

// ---------- GEMM: C[M][N] = A[M][K](bf16) * Bt[N][K](bf16)^T ----------
// EPI 0: bf16 out.  EPI 1: f32 out = acc + bias[col] + res[row*ldc+col].
// EPI 2: GEGLU: paired 16-col blocks (a,gate) -> bf16 a*gelu(gate), out ld = ldc.
template <int EPI>
__global__ __launch_bounds__(256) void gemm_bt_kernel(
    const u16* __restrict__ A, int lda, const u16* __restrict__ Bt,
    void* __restrict__ Cv, int ldc, const float* __restrict__ bias,
    const float* __restrict__ res, int M, int N, int K) {
  __shared__ __align__(16) u16 As[128 * 32];
  __shared__ __align__(16) u16 Bs[128 * 32];
  int t = threadIdx.x;
  int l = t & 63, w = t >> 6;
  int wm = w >> 1, wn = w & 1;
  int lr = l & 15, lg = l >> 4;
  int row0 = blockIdx.y * 128, n0 = blockIdx.x * 128;
  int srow = t >> 2, scol = (t & 3) * 8;
  f32x4 acc[4][4];
#pragma unroll
  for (int i = 0; i < 4; ++i)
#pragma unroll
    for (int j = 0; j < 4; ++j) acc[i][j] = f32x4{0.f, 0.f, 0.f, 0.f};

  for (int k0 = 0; k0 < K; k0 += 32) {
#pragma unroll
    for (int q = 0; q < 2; ++q) {
      int r = q * 64 + srow;
      int gr = row0 + r; if (gr > M - 1) gr = M - 1;
      *reinterpret_cast<uint4*>(&As[r * 32 + scol]) =
          *reinterpret_cast<const uint4*>(&A[(size_t)gr * lda + k0 + scol]);
      *reinterpret_cast<uint4*>(&Bs[r * 32 + scol]) =
          *reinterpret_cast<const uint4*>(&Bt[(size_t)(n0 + r) * K + k0 + scol]);
    }
    __syncthreads();
    bf16x8 af[4], bfv[4];
#pragma unroll
    for (int mi = 0; mi < 4; ++mi) af[mi] = ld8s(&As[(wm * 64 + mi * 16 + lr) * 32 + lg * 8]);
#pragma unroll
    for (int ni = 0; ni < 4; ++ni) bfv[ni] = ld8s(&Bs[(wn * 64 + ni * 16 + lr) * 32 + lg * 8]);
#pragma unroll
    for (int mi = 0; mi < 4; ++mi)
#pragma unroll
      for (int ni = 0; ni < 4; ++ni)
        acc[mi][ni] = __builtin_amdgcn_mfma_f32_16x16x32_bf16(af[mi], bfv[ni], acc[mi][ni], 0, 0, 0);
    __syncthreads();
  }

#pragma unroll
  for (int mi = 0; mi < 4; ++mi) {
    int rowb = row0 + wm * 64 + mi * 16 + lg * 4;
    if (EPI == 2) {
#pragma unroll
      for (int p = 0; p < 2; ++p) {
        int colA = n0 + wn * 64 + p * 32 + lr;
        int colG = colA + 16;
        int ocol = ((n0 + wn * 64) >> 1) + p * 16 + lr;
#pragma unroll
        for (int r = 0; r < 4; ++r) {
          int grow = rowb + r;
          float av = acc[mi][2 * p][r] + bias[colA];
          float gv = acc[mi][2 * p + 1][r] + bias[colG];
          ((u16*)Cv)[(size_t)grow * ldc + ocol] = f2bf(av * geluf(gv));
        }
      }
    } else {
#pragma unroll
      for (int ni = 0; ni < 4; ++ni) {
        int gcol = n0 + wn * 64 + ni * 16 + lr;
#pragma unroll
        for (int r = 0; r < 4; ++r) {
          int grow = rowb + r;
          if (grow >= M) continue;
          float v = acc[mi][ni][r];
          if (EPI == 0)
            ((u16*)Cv)[(size_t)grow * ldc + gcol] = f2bf(v);
          else
            ((float*)Cv)[(size_t)grow * ldc + gcol] =
                v + bias[gcol] + res[(size_t)grow * ldc + gcol];
        }
      }
    }
  }
}

// ---------- fused attention (flash-style, online softmax) ----------
// grid (N/64, H, B), 256 threads = 4 waves, each wave owns 16 q-rows.
__global__ __launch_bounds__(256) void attn_kernel(
    const u16* __restrict__ Q, int qs, int qoff,
    const u16* __restrict__ KV, int kvs, int koff, int voff,
    int m, u16* __restrict__ O) {
  const float SCALE = 0.125f;  // 64^-0.5
  int b = blockIdx.z, h = blockIdx.y;
  int t = threadIdx.x;
  int l = t & 63, w = t >> 6;
  int lr = l & 15, lg = l >> 4;
  int q0 = blockIdx.x * 64 + w * 16;
  __shared__ __align__(16) u16 Ks[32 * 64];
  __shared__ __align__(16) u16 Vt[64 * 32];
  __shared__ __align__(16) u16 Pl[4][16 * 32];

  const u16* qrow = Q + (size_t)((b << 11) + q0 + lr) * qs + qoff + h * 64;
  bf16x8 qf0 = ld8s(qrow + lg * 8);
  bf16x8 qf1 = ld8s(qrow + 32 + lg * 8);

  f32x4 o[4];
  float mrun[4], lrun[4];
#pragma unroll
  for (int r = 0; r < 4; ++r) { o[r] = f32x4{0.f, 0.f, 0.f, 0.f}; mrun[r] = -1e30f; lrun[r] = 0.f; }

  int sjr = t >> 3, sck = t & 7;
  int nj = (m + 31) >> 5;
  for (int jt = 0; jt < nj; ++jt) {
    int j0 = jt << 5;
    {
      int gj = j0 + sjr; if (gj > m - 1) gj = m - 1;
      const u16* krow = KV + (size_t)(b * m + gj) * kvs + h * 64;
      *reinterpret_cast<uint4*>(&Ks[sjr * 64 + sck * 8]) =
          *reinterpret_cast<const uint4*>(krow + koff + sck * 8);
      uint4 vv = *reinterpret_cast<const uint4*>(krow + voff + sck * 8);
      const u16* vp = reinterpret_cast<const u16*>(&vv);
#pragma unroll
      for (int i = 0; i < 8; ++i) Vt[(sck * 8 + i) * 32 + sjr] = vp[i];
    }
    __syncthreads();
    f32x4 s0 = f32x4{0.f, 0.f, 0.f, 0.f}, s1 = f32x4{0.f, 0.f, 0.f, 0.f};
    {
      bf16x8 ka = ld8s(&Ks[lr * 64 + lg * 8]);
      bf16x8 kb = ld8s(&Ks[lr * 64 + 32 + lg * 8]);
      s0 = __builtin_amdgcn_mfma_f32_16x16x32_bf16(qf0, ka, s0, 0, 0, 0);
      s0 = __builtin_amdgcn_mfma_f32_16x16x32_bf16(qf1, kb, s0, 0, 0, 0);
      bf16x8 kc = ld8s(&Ks[(16 + lr) * 64 + lg * 8]);
      bf16x8 kd = ld8s(&Ks[(16 + lr) * 64 + 32 + lg * 8]);
      s1 = __builtin_amdgcn_mfma_f32_16x16x32_bf16(qf0, kc, s1, 0, 0, 0);
      s1 = __builtin_amdgcn_mfma_f32_16x16x32_bf16(qf1, kd, s1, 0, 0, 0);
    }
    float pm[4];
    int c0 = j0 + lr, c1 = j0 + 16 + lr;
#pragma unroll
    for (int r = 0; r < 4; ++r) {
      float a = s0[r] * SCALE; if (c0 >= m) a = -1e30f;
      float c = s1[r] * SCALE; if (c1 >= m) c = -1e30f;
      s0[r] = a; s1[r] = c;
      pm[r] = fmaxf(a, c);
    }
#pragma unroll
    for (int d = 1; d < 16; d <<= 1)
#pragma unroll
      for (int r = 0; r < 4; ++r) pm[r] = fmaxf(pm[r], __shfl_xor(pm[r], d, 64));
    float alpha[4], rs[4];
#pragma unroll
    for (int r = 0; r < 4; ++r) {
      float mn = fmaxf(mrun[r], pm[r]);
      alpha[r] = __expf(mrun[r] - mn);
      mrun[r] = mn;
      float p0 = __expf(s0[r] - mn);
      float p1 = __expf(s1[r] - mn);
      rs[r] = p0 + p1;
      Pl[w][(lg * 4 + r) * 32 + lr] = f2bf(p0);
      Pl[w][(lg * 4 + r) * 32 + 16 + lr] = f2bf(p1);
    }
#pragma unroll
    for (int d = 1; d < 16; d <<= 1)
#pragma unroll
      for (int r = 0; r < 4; ++r) rs[r] += __shfl_xor(rs[r], d, 64);
#pragma unroll
    for (int r = 0; r < 4; ++r) lrun[r] = lrun[r] * alpha[r] + rs[r];
#pragma unroll
    for (int db = 0; db < 4; ++db)
#pragma unroll
      for (int r = 0; r < 4; ++r) o[db][r] *= alpha[r];
    __syncthreads();
    bf16x8 pa = ld8s(&Pl[w][lr * 32 + lg * 8]);
#pragma unroll
    for (int db = 0; db < 4; ++db) {
      bf16x8 vf = ld8s(&Vt[(db * 16 + lr) * 32 + lg * 8]);
      o[db] = __builtin_amdgcn_mfma_f32_16x16x32_bf16(pa, vf, o[db], 0, 0, 0);
    }
    __syncthreads();
  }
#pragma unroll
  for (int r = 0; r < 4; ++r) {
    float inv = 1.f / lrun[r];
    int grow = (b << 11) + q0 + lg * 4 + r;
    u16* op = O + (size_t)grow * 1024 + h * 64 + lr;
#pragma unroll
    for (int db = 0; db < 4; ++db) op[db * 16] = f2bf(o[db][r] * inv);
  }
}

extern "C" void kernel_launch(void* const* d_in, const int* in_sizes, int n_in,
                              void* d_out, int out_size, void* d_ws, size_t ws_size,
                              hipStream_t stream) {
  const float* x_in = (const float*)d_in[0];
  const float* ctx_in = (const float*)d_in[1];
  const float* hint_in = (const float*)d_in[2];
  const float* ln1g = (const float*)d_in[3]; const float* ln1b = (const float*)d_in[4];
  const float* ln2g = (const float*)d_in[5]; const float* ln2b = (const float*)d_in[6];
  const float* ln3g = (const float*)d_in[7]; const float* ln3b = (const float*)d_in[8];
  const float* ln4g = (const float*)d_in[9]; const float* ln4b = (const float*)d_in[10];
  const float* a1wq = (const float*)d_in[11]; const float* a1wk = (const float*)d_in[12];
  const float* a1wv = (const float*)d_in[13]; const float* a1wo = (const float*)d_in[14];
  const float* a1bo = (const float*)d_in[15];
  const float* a2wq = (const float*)d_in[16]; const float* a2wk = (const float*)d_in[17];
  const float* a2wv = (const float*)d_in[18]; const float* a2wo = (const float*)d_in[19];
  const float* a2bo = (const float*)d_in[20];
  const float* a3wq = (const float*)d_in[21]; const float* a3wk = (const float*)d_in[22];
  const float* a3wv = (const float*)d_in[23]; const float* a3wo = (const float*)d_in[24];
  const float* a3bo = (const float*)d_in[25];
  const float* ffw1 = (const float*)d_in[26]; const float* ffb1 = (const float*)d_in[27];
  const float* ffw2 = (const float*)d_in[28]; const float* ffb2 = (const float*)d_in[29];

  char* wsb = (char*)d_ws;
  size_t off = 0;
  auto alloc = [&](size_t bytes) -> void* {
    void* p = wsb + off;
    off += (bytes + 255) & ~(size_t)255;
    return p;
  };
  u16* wqkv1t = (u16*)alloc(3072ull * 1024 * 2);
  u16* wo1t = (u16*)alloc(1024ull * 1024 * 2);
  u16* wq2t = (u16*)alloc(1024ull * 1024 * 2);
  u16* wkv2t = (u16*)alloc(2048ull * 1024 * 2);
  u16* wo2t = (u16*)alloc(1024ull * 1024 * 2);
  u16* wq3t = (u16*)alloc(1024ull * 1024 * 2);
  u16* wkv3t = (u16*)alloc(2048ull * 1024 * 2);
  u16* wo3t = (u16*)alloc(1024ull * 1024 * 2);
  u16* w1t = (u16*)alloc(8192ull * 1024 * 2);
  u16* w2t = (u16*)alloc(1024ull * 4096 * 2);
  float* b1p = (float*)alloc(8192ull * 4);
  u16* hintbf = (u16*)alloc(500ull * 1024 * 2);
  u16* ctxbf = (u16*)alloc(512ull * 1024 * 2);
  float* xbuf = (float*)alloc(4096ull * 1024 * 4);
  u16* hbf = (u16*)alloc(4096ull * 1024 * 2);
  u16* attnout = (u16*)alloc(4096ull * 1024 * 2);
  u16* qbuf = (u16*)alloc(4096ull * 1024 * 2);
  u16* kvbuf = (u16*)alloc(512ull * 2048 * 2);
  u16* qkv = (u16*)alloc(4096ull * 4096 * 2);  // union: qkv [4096][3072] / g [4096][4096]
  u16* gbuf = qkv;

  dim3 tb(32, 8);
  // weight transposes -> bf16 W^T
  tcvt_kernel<<<dim3(32, 32), tb, 0, stream>>>(a1wq, wqkv1t, 1024, 1024, 0, 0, 1024);
  tcvt_kernel<<<dim3(32, 32), tb, 0, stream>>>(a1wk, wqkv1t, 1024, 1024, 0, 1024, 1024);
  tcvt_kernel<<<dim3(32, 32), tb, 0, stream>>>(a1wv, wqkv1t, 1024, 1024, 0, 2048, 1024);
  tcvt_kernel<<<dim3(32, 32), tb, 0, stream>>>(a1wo, wo1t, 1024, 1024, 0, 0, 1024);
  tcvt_kernel<<<dim3(32, 32), tb, 0, stream>>>(a2wq, wq2t, 1024, 1024, 0, 0, 1024);
  tcvt_kernel<<<dim3(32, 32), tb, 0, stream>>>(a2wk, wkv2t, 1024, 1024, 0, 0, 1024);
  tcvt_kernel<<<dim3(32, 32), tb, 0, stream>>>(a2wv, wkv2t, 1024, 1024, 0, 1024, 1024);
  tcvt_kernel<<<dim3(32, 32), tb, 0, stream>>>(a2wo, wo2t, 1024, 1024, 0, 0, 1024);
  tcvt_kernel<<<dim3(32, 32), tb, 0, stream>>>(a3wq, wq3t, 1024, 1024, 0, 0, 1024);
  tcvt_kernel<<<dim3(32, 32), tb, 0, stream>>>(a3wk, wkv3t, 1024, 1024, 0, 0, 1024);
  tcvt_kernel<<<dim3(32, 32), tb, 0, stream>>>(a3wv, wkv3t, 1024, 1024, 0, 1024, 1024);
  tcvt_kernel<<<dim3(32, 32), tb, 0, stream>>>(a3wo, wo3t, 1024, 1024, 0, 0, 1024);
  tcvt_kernel<<<dim3(256, 32), tb, 0, stream>>>(ffw1, w1t, 1024, 8192, 1, 0, 1024);
  tcvt_kernel<<<dim3(32, 128), tb, 0, stream>>>(ffw2, w2t, 4096, 1024, 0, 0, 4096);
  b1remap_kernel<<<32, 256, 0, stream>>>(ffb1, b1p);
  cvt_kernel<<<2048, 256, 0, stream>>>(ctx_in, ctxbf, 524288);
  peadd_kernel<<<500, 256, 0, stream>>>(hint_in, hintbf);

  // ---- stage 1: self-attention ----
  ln_kernel<<<4096, 256, 0, stream>>>(x_in, ln1g, ln1b, hbf);
  gemm_bt_kernel<0><<<dim3(24, 32), 256, 0, stream>>>(hbf, 1024, wqkv1t, qkv, 3072,
                                                      nullptr, nullptr, 4096, 3072, 1024);
  attn_kernel<<<dim3(32, 16, 2), 256, 0, stream>>>(qkv, 3072, 0, qkv, 3072, 1024, 2048,
                                                   2048, attnout);
  gemm_bt_kernel<1><<<dim3(8, 32), 256, 0, stream>>>(attnout, 1024, wo1t, xbuf, 1024,
                                                     a1bo, x_in, 4096, 1024, 1024);

  // ---- stage 2: cross-attention over context ----
  ln_kernel<<<4096, 256, 0, stream>>>(xbuf, ln2g, ln2b, hbf);
  gemm_bt_kernel<0><<<dim3(8, 32), 256, 0, stream>>>(hbf, 1024, wq2t, qbuf, 1024,
                                                     nullptr, nullptr, 4096, 1024, 1024);
  gemm_bt_kernel<0><<<dim3(16, 4), 256, 0, stream>>>(ctxbf, 1024, wkv2t, kvbuf, 2048,
                                                     nullptr, nullptr, 512, 2048, 1024);
  attn_kernel<<<dim3(32, 16, 2), 256, 0, stream>>>(qbuf, 1024, 0, kvbuf, 2048, 0, 1024,
                                                   256, attnout);
  gemm_bt_kernel<1><<<dim3(8, 32), 256, 0, stream>>>(attnout, 1024, wo2t, xbuf, 1024,
                                                     a2bo, xbuf, 4096, 1024, 1024);

  // ---- stage 3: video cross-attention (uses ln4) ----
  ln_kernel<<<4096, 256, 0, stream>>>(xbuf, ln4g, ln4b, hbf);
  gemm_bt_kernel<0><<<dim3(8, 32), 256, 0, stream>>>(hbf, 1024, wq3t, qbuf, 1024,
                                                     nullptr, nullptr, 4096, 1024, 1024);
  gemm_bt_kernel<0><<<dim3(16, 4), 256, 0, stream>>>(hintbf, 1024, wkv3t, kvbuf, 2048,
                                                     nullptr, nullptr, 500, 2048, 1024);
  attn_kernel<<<dim3(32, 16, 2), 256, 0, stream>>>(qbuf, 1024, 0, kvbuf, 2048, 0, 1024,
                                                   250, attnout);
  gemm_bt_kernel<1><<<dim3(8, 32), 256, 0, stream>>>(attnout, 1024, wo3t, xbuf, 1024,
                                                     a3bo, xbuf, 4096, 1024, 1024);

  // ---- GEGLU feed-forward (uses ln3) ----
  ln_kernel<<<4096, 256, 0, stream>>>(xbuf, ln3g, ln3b, hbf);
  gemm_bt_kernel<2><<<dim3(64, 32), 256, 0, stream>>>(hbf, 1024, w1t, gbuf, 4096,
                                                      b1p, nullptr, 4096, 8192, 1024);
  gemm_bt_kernel<1><<<dim3(8, 32), 256, 0, stream>>>(gbuf, 4096, w2t, d_out, 1024,
                                                     ffb2, xbuf, 4096, 1024, 4096);
}

// Round 2
// 703.822 us; speedup vs baseline: 1.1815x; 1.1815x over previous
//
#include <hip/hip_runtime.h>
#include <cstdint>

typedef unsigned short u16;
typedef __bf16 bf16x8 __attribute__((ext_vector_type(8)));
typedef float f32x4 __attribute__((ext_vector_type(4)));

__device__ __forceinline__ u16 f2bf(float f) {
  union { float f; uint32_t u; } x; x.f = f;
  uint32_t r = x.u + 0x7FFFu + ((x.u >> 16) & 1u);
  return (u16)(r >> 16);
}
__device__ __forceinline__ bf16x8 ld8s(const u16* p) {
  return *reinterpret_cast<const bf16x8*>(p);
}
__device__ __forceinline__ float geluf(float x) {
  return 0.5f * x * (1.f + erff(x * 0.70710678118654752f));
}
// async global->LDS, 16B per lane; lds dest must be wave-uniform base (+lane*16)
__device__ __forceinline__ void gload16(const u16* g, u16* l) {
  __builtin_amdgcn_global_load_lds(
      (__attribute__((address_space(1))) void*)const_cast<u16*>(g),
      (__attribute__((address_space(3))) void*)l, 16, 0, 0);
}

// ---------- transpose + f32->bf16 convert: out[orow][k] = in[k][n] ----------
__global__ void tcvt_kernel(const float* __restrict__ in, u16* __restrict__ out,
                            int K, int N, int mode, int row_off, int ldo) {
  __shared__ float tile[32][33];
  int n = blockIdx.x * 32 + threadIdx.x;
  int kbase = blockIdx.y * 32;
#pragma unroll
  for (int r = 0; r < 4; ++r) {
    int k = kbase + threadIdx.y + r * 8;
    tile[threadIdx.y + r * 8][threadIdx.x] = in[(size_t)k * N + n];
  }
  __syncthreads();
#pragma unroll
  for (int r = 0; r < 4; ++r) {
    int nl = threadIdx.y + r * 8;
    int ng = blockIdx.x * 32 + nl;
    int orow;
    if (mode == 0) {
      orow = row_off + ng;
    } else {
      if (ng < 4096) orow = ((ng >> 4) << 5) + (ng & 15);
      else { int t2 = ng - 4096; orow = ((t2 >> 4) << 5) + 16 + (t2 & 15); }
    }
    int k = kbase + threadIdx.x;
    out[(size_t)orow * ldo + k] = f2bf(tile[threadIdx.x][nl]);
  }
}

__global__ void b1remap_kernel(const float* __restrict__ b1, float* __restrict__ b1p) {
  int i = blockIdx.x * 256 + threadIdx.x;
  int g = i >> 5, s = i & 31;
  int c = (s < 16) ? (g * 16 + s) : (4096 + g * 16 + (s - 16));
  b1p[i] = b1[c];
}

__global__ void cvt_kernel(const float* __restrict__ in, u16* __restrict__ out, int n) {
  int i = blockIdx.x * 256 + threadIdx.x;
  if (i < n) out[i] = f2bf(in[i]);
}

__global__ void peadd_kernel(const float* __restrict__ hint, u16* __restrict__ out) {
  int row = blockIdx.x;
  int t = row % 250;
  int tid = threadIdx.x;
  int d0 = tid * 4;
  int i0 = d0 >> 1;
  float den0 = powf(10000.f, (float)i0 / 512.f);
  float den1 = powf(10000.f, (float)(i0 + 1) / 512.f);
  float a0 = (float)t / den0, a1 = (float)t / den1;
  const float* hp = hint + (size_t)row * 1024 + d0;
  u16* op = out + (size_t)row * 1024 + d0;
  op[0] = f2bf(hp[0] + sinf(a0));
  op[1] = f2bf(hp[1] + cosf(a0));
  op[2] = f2bf(hp[2] + sinf(a1));
  op[3] = f2bf(hp[3] + cosf(a1));
}

// ---------- LayerNorm: f32 [rows][1024] -> bf16 ----------
__global__ __launch_bounds__(256) void ln_kernel(const float* __restrict__ x,
                                                 const float* __restrict__ g,
                                                 const float* __restrict__ b,
                                                 u16* __restrict__ out) {
  int row = blockIdx.x;
  int tid = threadIdx.x;
  int l = tid & 63, w = tid >> 6;
  const float4 v = reinterpret_cast<const float4*>(x + (size_t)row * 1024)[tid];
  float s = v.x + v.y + v.z + v.w;
#pragma unroll
  for (int d = 1; d < 64; d <<= 1) s += __shfl_xor(s, d, 64);
  __shared__ float red[8];
  if (l == 0) red[w] = s;
  __syncthreads();
  float mean = (red[0] + red[1] + red[2] + red[3]) * (1.f / 1024.f);
  float dx = v.x - mean, dy = v.y - mean, dz = v.z - mean, dw = v.w - mean;
  float vs = dx * dx + dy * dy + dz * dz + dw * dw;
#pragma unroll
  for (int d = 1; d < 64; d <<= 1) vs += __shfl_xor(vs, d, 64);
  if (l == 0) red[4 + w] = vs;
  __syncthreads();
  float var = (red[4] + red[5] + red[6] + red[7]) * (1.f / 1024.f);
  float rstd = rsqrtf(var + 1e-5f);
  const float4 g4 = reinterpret_cast<const float4*>(g)[tid];
  const float4 b4 = reinterpret_cast<const float4*>(b)[tid];
  ushort4 o;
  o.x = f2bf(dx * rstd * g4.x + b4.x);
  o.y = f2bf(dy * rstd * g4.y + b4.y);
  o.z = f2bf(dz * rstd * g4.z + b4.z);
  o.w = f2bf(dw * rstd * g4.w + b4.w);
  reinterpret_cast<ushort4*>(out + (size_t)row * 1024)[tid] = o;
}

// ---------- GEMM: C[M][N] = A[M][K](bf16) * Bt[N][K](bf16)^T ----------
// m97 structure: global_load_lds width-16 staging, 128x128 tile, BK=32.
template <int EPI>
__global__ __launch_bounds__(256) void gemm_bt_kernel(
    const u16* __restrict__ A, int lda, const u16* __restrict__ Bt,
    void* __restrict__ Cv, int ldc, const float* __restrict__ bias,
    const float* __restrict__ res, int M, int N, int K) {
  __shared__ __align__(16) u16 As[128 * 32];
  __shared__ __align__(16) u16 Bs[128 * 32];
  int t = threadIdx.x;
  int l = t & 63, w = t >> 6;
  int wm = w >> 1, wn = w & 1;
  int lr = l & 15, lg = l >> 4;
  int row0 = blockIdx.y * 128, n0 = blockIdx.x * 128;
  int lrow = l >> 2, lcol = (l & 3) * 8;  // lane -> (row-in-16, 8-u16 chunk)
  f32x4 acc[4][4];
#pragma unroll
  for (int i = 0; i < 4; ++i)
#pragma unroll
    for (int j = 0; j < 4; ++j) acc[i][j] = f32x4{0.f, 0.f, 0.f, 0.f};

  for (int k0 = 0; k0 < K; k0 += 32) {
#pragma unroll
    for (int q = 0; q < 2; ++q) {
      int rbase = w * 32 + q * 16;
      int ga = row0 + rbase + lrow; if (ga > M - 1) ga = M - 1;
      gload16(&A[(size_t)ga * lda + k0 + lcol], &As[rbase * 32]);
      int gb = n0 + rbase + lrow;
      gload16(&Bt[(size_t)gb * K + k0 + lcol], &Bs[rbase * 32]);
    }
    __syncthreads();
    bf16x8 af[4], bfv[4];
#pragma unroll
    for (int mi = 0; mi < 4; ++mi) af[mi] = ld8s(&As[(wm * 64 + mi * 16 + lr) * 32 + lg * 8]);
#pragma unroll
    for (int ni = 0; ni < 4; ++ni) bfv[ni] = ld8s(&Bs[(wn * 64 + ni * 16 + lr) * 32 + lg * 8]);
#pragma unroll
    for (int mi = 0; mi < 4; ++mi)
#pragma unroll
      for (int ni = 0; ni < 4; ++ni)
        acc[mi][ni] = __builtin_amdgcn_mfma_f32_16x16x32_bf16(af[mi], bfv[ni], acc[mi][ni], 0, 0, 0);
    __syncthreads();
  }

#pragma unroll
  for (int mi = 0; mi < 4; ++mi) {
    int rowb = row0 + wm * 64 + mi * 16 + lg * 4;
    if (EPI == 2) {
#pragma unroll
      for (int p = 0; p < 2; ++p) {
        int colA = n0 + wn * 64 + p * 32 + lr;
        int colG = colA + 16;
        int ocol = ((n0 + wn * 64) >> 1) + p * 16 + lr;
#pragma unroll
        for (int r = 0; r < 4; ++r) {
          int grow = rowb + r;
          float av = acc[mi][2 * p][r] + bias[colA];
          float gv = acc[mi][2 * p + 1][r] + bias[colG];
          ((u16*)Cv)[(size_t)grow * ldc + ocol] = f2bf(av * geluf(gv));
        }
      }
    } else {
#pragma unroll
      for (int ni = 0; ni < 4; ++ni) {
        int gcol = n0 + wn * 64 + ni * 16 + lr;
#pragma unroll
        for (int r = 0; r < 4; ++r) {
          int grow = rowb + r;
          if (grow >= M) continue;
          float v = acc[mi][ni][r];
          if (EPI == 0)
            ((u16*)Cv)[(size_t)grow * ldc + gcol] = f2bf(v);
          else
            ((float*)Cv)[(size_t)grow * ldc + gcol] =
                v + bias[gcol] + res[(size_t)grow * ldc + gcol];
        }
      }
    }
  }
}

// ---------- fused attention (flash-style, online softmax) ----------
// grid (N/64, H, B), 256 threads = 4 waves, each wave owns 16 q-rows.
// KVBLK=64; K in padded LDS [64][72]; V transposed+XOR-swizzled; P padded [16][72].
__global__ __launch_bounds__(256) void attn_kernel(
    const u16* __restrict__ Q, int qs, int qoff,
    const u16* __restrict__ KV, int kvs, int koff, int voff,
    int m, u16* __restrict__ O) {
  const float SCALE = 0.125f;  // 64^-0.5
  int b = blockIdx.z, h = blockIdx.y;
  int t = threadIdx.x;
  int l = t & 63, w = t >> 6;
  int lr = l & 15, lg = l >> 4;
  int q0 = blockIdx.x * 64 + w * 16;
  __shared__ __align__(16) u16 Ks[64 * 72];
  __shared__ __align__(16) u16 Vt[64 * 64];   // (d,j) -> d*64 + ((j>>3 ^ key(d))*8 + (j&7))
  __shared__ __align__(16) u16 Pl[4][16 * 72];

  const u16* qrow = Q + (size_t)((b << 11) + q0 + lr) * qs + qoff + h * 64;
  bf16x8 qf0 = ld8s(qrow + lg * 8);
  bf16x8 qf1 = ld8s(qrow + 32 + lg * 8);

  f32x4 o[4];
  float mrun[4], lrun[4];
#pragma unroll
  for (int r = 0; r < 4; ++r) { o[r] = f32x4{0.f, 0.f, 0.f, 0.f}; mrun[r] = -1e30f; lrun[r] = 0.f; }

  int kj = t >> 3, kc = t & 7;  // staging: row, 8-u16 chunk
  const u16* kvb = KV + (size_t)b * m * kvs + h * 64;

  int nj = (m + 63) >> 6;
  for (int jt = 0; jt < nj; ++jt) {
    int j0 = jt << 6;
    // ---- stage K rows (kj, kj+32) and V row-pair (2kj, 2kj+1) ----
    {
      int g0 = j0 + kj; if (g0 > m - 1) g0 = m - 1;
      int g1 = j0 + kj + 32; if (g1 > m - 1) g1 = m - 1;
      *reinterpret_cast<uint4*>(&Ks[kj * 72 + kc * 8]) =
          *reinterpret_cast<const uint4*>(kvb + (size_t)g0 * kvs + koff + kc * 8);
      *reinterpret_cast<uint4*>(&Ks[(kj + 32) * 72 + kc * 8]) =
          *reinterpret_cast<const uint4*>(kvb + (size_t)g1 * kvs + koff + kc * 8);
      int jv = kj * 2;
      int gv0 = j0 + jv; if (gv0 > m - 1) gv0 = m - 1;
      int gv1 = j0 + jv + 1; if (gv1 > m - 1) gv1 = m - 1;
      uint4 va = *reinterpret_cast<const uint4*>(kvb + (size_t)gv0 * kvs + voff + kc * 8);
      uint4 vb2 = *reinterpret_cast<const uint4*>(kvb + (size_t)gv1 * kvs + voff + kc * 8);
      const u16* vap = reinterpret_cast<const u16*>(&va);
      const u16* vbp = reinterpret_cast<const u16*>(&vb2);
      int jb = jv >> 3, jlow = jv & 7;
#pragma unroll
      for (int i = 0; i < 8; ++i) {
        int d = kc * 8 + i;
        int key = (d ^ (d >> 3)) & 7;
        uint32_t pk = (uint32_t)vap[i] | ((uint32_t)vbp[i] << 16);
        *reinterpret_cast<uint32_t*>(&Vt[d * 64 + ((jb ^ key) << 3) + jlow]) = pk;
      }
    }
    __syncthreads();

    // ---- QK^T: S[16 q][64 j] per wave ----
    f32x4 s[4];
#pragma unroll
    for (int c = 0; c < 4; ++c) s[c] = f32x4{0.f, 0.f, 0.f, 0.f};
#pragma unroll
    for (int c = 0; c < 4; ++c) {
      bf16x8 k0 = ld8s(&Ks[(c * 16 + lr) * 72 + lg * 8]);
      s[c] = __builtin_amdgcn_mfma_f32_16x16x32_bf16(qf0, k0, s[c], 0, 0, 0);
      bf16x8 k1 = ld8s(&Ks[(c * 16 + lr) * 72 + 32 + lg * 8]);
      s[c] = __builtin_amdgcn_mfma_f32_16x16x32_bf16(qf1, k1, s[c], 0, 0, 0);
    }

    // ---- online softmax ----
    float pm[4];
#pragma unroll
    for (int r = 0; r < 4; ++r) {
#pragma unroll
      for (int c = 0; c < 4; ++c) {
        float v = s[c][r] * SCALE;
        if (j0 + c * 16 + lr >= m) v = -1e30f;
        s[c][r] = v;
      }
      pm[r] = fmaxf(fmaxf(s[0][r], s[1][r]), fmaxf(s[2][r], s[3][r]));
    }
#pragma unroll
    for (int d = 1; d < 16; d <<= 1)
#pragma unroll
      for (int r = 0; r < 4; ++r) pm[r] = fmaxf(pm[r], __shfl_xor(pm[r], d, 64));
    float alpha[4], rs[4];
#pragma unroll
    for (int r = 0; r < 4; ++r) {
      float mn = fmaxf(mrun[r], pm[r]);
      alpha[r] = __expf(mrun[r] - mn);
      mrun[r] = mn;
      rs[r] = 0.f;
#pragma unroll
      for (int c = 0; c < 4; ++c) {
        float p = __expf(s[c][r] - mn);
        rs[r] += p;
        Pl[w][(lg * 4 + r) * 72 + c * 16 + lr] = f2bf(p);
      }
    }
#pragma unroll
    for (int d = 1; d < 16; d <<= 1)
#pragma unroll
      for (int r = 0; r < 4; ++r) rs[r] += __shfl_xor(rs[r], d, 64);
#pragma unroll
    for (int r = 0; r < 4; ++r) lrun[r] = lrun[r] * alpha[r] + rs[r];
#pragma unroll
    for (int dt = 0; dt < 4; ++dt)
#pragma unroll
      for (int r = 0; r < 4; ++r) o[dt][r] *= alpha[r];

    // ---- PV: O[16 q][64 d] += P[16][64] * V[64][64] ----
#pragma unroll
    for (int ks = 0; ks < 2; ++ks) {
      bf16x8 pa = ld8s(&Pl[w][lr * 72 + ks * 32 + lg * 8]);
#pragma unroll
      for (int dt = 0; dt < 4; ++dt) {
        int d = dt * 16 + lr;
        int key = (d ^ (d >> 3)) & 7;
        bf16x8 vf = ld8s(&Vt[d * 64 + ((((ks << 2) + lg) ^ key) << 3)]);
        o[dt] = __builtin_amdgcn_mfma_f32_16x16x32_bf16(pa, vf, o[dt], 0, 0, 0);
      }
    }
    __syncthreads();
  }

#pragma unroll
  for (int r = 0; r < 4; ++r) {
    float inv = 1.f / lrun[r];
    int grow = (b << 11) + q0 + lg * 4 + r;
    u16* op = O + (size_t)grow * 1024 + h * 64 + lr;
#pragma unroll
    for (int dt = 0; dt < 4; ++dt) op[dt * 16] = f2bf(o[dt][r] * inv);
  }
}

extern "C" void kernel_launch(void* const* d_in, const int* in_sizes, int n_in,
                              void* d_out, int out_size, void* d_ws, size_t ws_size,
                              hipStream_t stream) {
  const float* x_in = (const float*)d_in[0];
  const float* ctx_in = (const float*)d_in[1];
  const float* hint_in = (const float*)d_in[2];
  const float* ln1g = (const float*)d_in[3]; const float* ln1b = (const float*)d_in[4];
  const float* ln2g = (const float*)d_in[5]; const float* ln2b = (const float*)d_in[6];
  const float* ln3g = (const float*)d_in[7]; const float* ln3b = (const float*)d_in[8];
  const float* ln4g = (const float*)d_in[9]; const float* ln4b = (const float*)d_in[10];
  const float* a1wq = (const float*)d_in[11]; const float* a1wk = (const float*)d_in[12];
  const float* a1wv = (const float*)d_in[13]; const float* a1wo = (const float*)d_in[14];
  const float* a1bo = (const float*)d_in[15];
  const float* a2wq = (const float*)d_in[16]; const float* a2wk = (const float*)d_in[17];
  const float* a2wv = (const float*)d_in[18]; const float* a2wo = (const float*)d_in[19];
  const float* a2bo = (const float*)d_in[20];
  const float* a3wq = (const float*)d_in[21]; const float* a3wk = (const float*)d_in[22];
  const float* a3wv = (const float*)d_in[23]; const float* a3wo = (const float*)d_in[24];
  const float* a3bo = (const float*)d_in[25];
  const float* ffw1 = (const float*)d_in[26]; const float* ffb1 = (const float*)d_in[27];
  const float* ffw2 = (const float*)d_in[28]; const float* ffb2 = (const float*)d_in[29];

  char* wsb = (char*)d_ws;
  size_t off = 0;
  auto alloc = [&](size_t bytes) -> void* {
    void* p = wsb + off;
    off += (bytes + 255) & ~(size_t)255;
    return p;
  };
  u16* wqkv1t = (u16*)alloc(3072ull * 1024 * 2);
  u16* wo1t = (u16*)alloc(1024ull * 1024 * 2);
  u16* wq2t = (u16*)alloc(1024ull * 1024 * 2);
  u16* wkv2t = (u16*)alloc(2048ull * 1024 * 2);
  u16* wo2t = (u16*)alloc(1024ull * 1024 * 2);
  u16* wq3t = (u16*)alloc(1024ull * 1024 * 2);
  u16* wkv3t = (u16*)alloc(2048ull * 1024 * 2);
  u16* wo3t = (u16*)alloc(1024ull * 1024 * 2);
  u16* w1t = (u16*)alloc(8192ull * 1024 * 2);
  u16* w2t = (u16*)alloc(1024ull * 4096 * 2);
  float* b1p = (float*)alloc(8192ull * 4);
  u16* hintbf = (u16*)alloc(500ull * 1024 * 2);
  u16* ctxbf = (u16*)alloc(512ull * 1024 * 2);
  float* xbuf = (float*)alloc(4096ull * 1024 * 4);
  u16* hbf = (u16*)alloc(4096ull * 1024 * 2);
  u16* attnout = (u16*)alloc(4096ull * 1024 * 2);
  u16* qbuf = (u16*)alloc(4096ull * 1024 * 2);
  u16* kvbuf = (u16*)alloc(512ull * 2048 * 2);
  u16* qkv = (u16*)alloc(4096ull * 4096 * 2);  // union: qkv [4096][3072] / g [4096][4096]
  u16* gbuf = qkv;

  dim3 tb(32, 8);
  tcvt_kernel<<<dim3(32, 32), tb, 0, stream>>>(a1wq, wqkv1t, 1024, 1024, 0, 0, 1024);
  tcvt_kernel<<<dim3(32, 32), tb, 0, stream>>>(a1wk, wqkv1t, 1024, 1024, 0, 1024, 1024);
  tcvt_kernel<<<dim3(32, 32), tb, 0, stream>>>(a1wv, wqkv1t, 1024, 1024, 0, 2048, 1024);
  tcvt_kernel<<<dim3(32, 32), tb, 0, stream>>>(a1wo, wo1t, 1024, 1024, 0, 0, 1024);
  tcvt_kernel<<<dim3(32, 32), tb, 0, stream>>>(a2wq, wq2t, 1024, 1024, 0, 0, 1024);
  tcvt_kernel<<<dim3(32, 32), tb, 0, stream>>>(a2wk, wkv2t, 1024, 1024, 0, 0, 1024);
  tcvt_kernel<<<dim3(32, 32), tb, 0, stream>>>(a2wv, wkv2t, 1024, 1024, 0, 1024, 1024);
  tcvt_kernel<<<dim3(32, 32), tb, 0, stream>>>(a2wo, wo2t, 1024, 1024, 0, 0, 1024);
  tcvt_kernel<<<dim3(32, 32), tb, 0, stream>>>(a3wq, wq3t, 1024, 1024, 0, 0, 1024);
  tcvt_kernel<<<dim3(32, 32), tb, 0, stream>>>(a3wk, wkv3t, 1024, 1024, 0, 0, 1024);
  tcvt_kernel<<<dim3(32, 32), tb, 0, stream>>>(a3wv, wkv3t, 1024, 1024, 0, 1024, 1024);
  tcvt_kernel<<<dim3(32, 32), tb, 0, stream>>>(a3wo, wo3t, 1024, 1024, 0, 0, 1024);
  tcvt_kernel<<<dim3(256, 32), tb, 0, stream>>>(ffw1, w1t, 1024, 8192, 1, 0, 1024);
  tcvt_kernel<<<dim3(32, 128), tb, 0, stream>>>(ffw2, w2t, 4096, 1024, 0, 0, 4096);
  b1remap_kernel<<<32, 256, 0, stream>>>(ffb1, b1p);
  cvt_kernel<<<2048, 256, 0, stream>>>(ctx_in, ctxbf, 524288);
  peadd_kernel<<<500, 256, 0, stream>>>(hint_in, hintbf);

  // ---- stage 1: self-attention ----
  ln_kernel<<<4096, 256, 0, stream>>>(x_in, ln1g, ln1b, hbf);
  gemm_bt_kernel<0><<<dim3(24, 32), 256, 0, stream>>>(hbf, 1024, wqkv1t, qkv, 3072,
                                                      nullptr, nullptr, 4096, 3072, 1024);
  attn_kernel<<<dim3(32, 16, 2), 256, 0, stream>>>(qkv, 3072, 0, qkv, 3072, 1024, 2048,
                                                   2048, attnout);
  gemm_bt_kernel<1><<<dim3(8, 32), 256, 0, stream>>>(attnout, 1024, wo1t, xbuf, 1024,
                                                     a1bo, x_in, 4096, 1024, 1024);

  // ---- stage 2: cross-attention over context ----
  ln_kernel<<<4096, 256, 0, stream>>>(xbuf, ln2g, ln2b, hbf);
  gemm_bt_kernel<0><<<dim3(8, 32), 256, 0, stream>>>(hbf, 1024, wq2t, qbuf, 1024,
                                                     nullptr, nullptr, 4096, 1024, 1024);
  gemm_bt_kernel<0><<<dim3(16, 4), 256, 0, stream>>>(ctxbf, 1024, wkv2t, kvbuf, 2048,
                                                     nullptr, nullptr, 512, 2048, 1024);
  attn_kernel<<<dim3(32, 16, 2), 256, 0, stream>>>(qbuf, 1024, 0, kvbuf, 2048, 0, 1024,
                                                   256, attnout);
  gemm_bt_kernel<1><<<dim3(8, 32), 256, 0, stream>>>(attnout, 1024, wo2t, xbuf, 1024,
                                                     a2bo, xbuf, 4096, 1024, 1024);

  // ---- stage 3: video cross-attention (uses ln4) ----
  ln_kernel<<<4096, 256, 0, stream>>>(xbuf, ln4g, ln4b, hbf);
  gemm_bt_kernel<0><<<dim3(8, 32), 256, 0, stream>>>(hbf, 1024, wq3t, qbuf, 1024,
                                                     nullptr, nullptr, 4096, 1024, 1024);
  gemm_bt_kernel<0><<<dim3(16, 4), 256, 0, stream>>>(hintbf, 1024, wkv3t, kvbuf, 2048,
                                                     nullptr, nullptr, 500, 2048, 1024);
  attn_kernel<<<dim3(32, 16, 2), 256, 0, stream>>>(qbuf, 1024, 0, kvbuf, 2048, 0, 1024,
                                                   250, attnout);
  gemm_bt_kernel<1><<<dim3(8, 32), 256, 0, stream>>>(attnout, 1024, wo3t, xbuf, 1024,
                                                     a3bo, xbuf, 4096, 1024, 1024);

  // ---- GEGLU feed-forward (uses ln3) ----
  ln_kernel<<<4096, 256, 0, stream>>>(xbuf, ln3g, ln3b, hbf);
  gemm_bt_kernel<2><<<dim3(64, 32), 256, 0, stream>>>(hbf, 1024, w1t, gbuf, 4096,
                                                      b1p, nullptr, 4096, 8192, 1024);
  gemm_bt_kernel<1><<<dim3(8, 32), 256, 0, stream>>>(gbuf, 4096, w2t, d_out, 1024,
                                                     ffb2, xbuf, 4096, 1024, 4096);
}